// Round 15
// baseline (524.374 us; speedup 1.0000x reference)
//
#include <hip/hip_runtime.h>
#include <math.h>

// ---------------------------------------------------------------- constants
constexpr int N  = 40000;   // nodes
constexpr int D  = 128;     // latent dim
constexpr int E  = 640000;  // spatial edges
constexpr int Bg = 8;       // graphs
constexpr int Sg = 5000;    // nodes per graph
constexpr int KN = 6;       // knn
constexpr int FF = 256;     // ffn hidden
constexpr int CLEN = 640;   // candidate chunk length (64-aligned); chunk 7 = 520
constexpr int NCAND = 48;   // 8 chunks x top-6

typedef short short8 __attribute__((ext_vector_type(8)));
typedef float f32x4  __attribute__((ext_vector_type(4)));

// ---------------------------------------------------------------- bf16 helpers
__device__ __forceinline__ unsigned short f2bf(float f)
{
    unsigned int u = __float_as_uint(f);
    return (unsigned short)((u + 0x7fffu + ((u >> 16) & 1u)) >> 16);
}

// ---------------------------------------------------------------- W pre-transpose + bf16 cast + deg zero
__global__ __launch_bounds__(256) void w_prep_k(
    const float* __restrict__ W0, const float* __restrict__ W1,
    const float* __restrict__ W2, const float* __restrict__ W3,
    const float* __restrict__ Wc, const float* __restrict__ Wf1,
    const float* __restrict__ Wf2,
    unsigned short* __restrict__ wt4, unsigned short* __restrict__ wtc,
    unsigned short* __restrict__ wtf1, unsigned short* __restrict__ wtf2,
    int* __restrict__ deg)
{
    int idx = blockIdx.x * 256 + threadIdx.x;
    if (idx < N) deg[idx] = 0;                // fold memset
    if (idx < 65536) {                        // node transforms [128][128]
        int m = idx >> 14, rem = idx & 16383;
        int k = rem & 127, c = rem >> 7;
        const float* Wm = (m == 0) ? W0 : (m == 1) ? W1 : (m == 2) ? W2 : W3;
        wt4[m * 16384 + c * 128 + k] = f2bf(Wm[k * 128 + c]);
    } else if (idx < 98304) {                 // W_c [256][128] -> [128][256]
        int rem = idx - 65536; int k = rem & 255, c = rem >> 8;
        wtc[c * 256 + k] = f2bf(Wc[k * 128 + c]);
    } else if (idx < 131072) {                // W_f1 [128][256] -> [256][128]
        int rem = idx - 98304; int k = rem & 127, c = rem >> 7;
        wtf1[c * 128 + k] = f2bf(Wf1[k * 256 + c]);
    } else {                                  // W_f2 [256][128] -> [128][256]
        int rem = idx - 131072; int k = rem & 255, c = rem >> 8;
        wtf2[c * 256 + k] = f2bf(Wf2[k * 128 + c]);
    }
}

// ---------------------------------------------------------------- fused 4x node-transform MFMA GEMM
// blockIdx.y==0 blocks additionally emit xh (bf16 cast of x) and sqn (row norms).
__global__ __launch_bounds__(256) void gemm4_mfma_k(
    const float* __restrict__ A, const unsigned short* __restrict__ wt4,
    const float* __restrict__ b0, const float* __restrict__ b1,
    const float* __restrict__ b2, const float* __restrict__ b3,
    float* __restrict__ o0, float* __restrict__ o1,
    float* __restrict__ o2, float* __restrict__ o3,
    unsigned short* __restrict__ xh, float* __restrict__ sqn)
{
    const unsigned short* Wt = wt4 + blockIdx.y * 16384;
    const float* bias; float* out;
    if (blockIdx.y == 0)      { bias = b0; out = o0; }
    else if (blockIdx.y == 1) { bias = b1; out = o1; }
    else if (blockIdx.y == 2) { bias = b2; out = o2; }
    else                      { bias = b3; out = o3; }

    __shared__ float xs[64][36];
    __shared__ unsigned short ws[128][40];
    int tid = threadIdx.x;
    int w = tid >> 6, lane = tid & 63;
    int lg = lane >> 4, ln = lane & 15;
    int r0 = blockIdx.x * 64;

    f32x4 acc[8];
#pragma unroll
    for (int ct = 0; ct < 8; ++ct) acc[ct] = {0.f, 0.f, 0.f, 0.f};

    int srow = tid >> 2, sk8 = (tid & 3) * 8;
    int wcol = tid >> 1, wk = (tid & 1) * 16;
    bool emit = (blockIdx.y == 0);
    float sq = 0.f;

    for (int kt = 0; kt < 128; kt += 32) {
        __syncthreads();
        float4 v0 = *(const float4*)&A[(size_t)(r0 + srow) * 128 + kt + sk8];
        float4 v1 = *(const float4*)&A[(size_t)(r0 + srow) * 128 + kt + sk8 + 4];
        *(float4*)&xs[srow][sk8]     = v0;
        *(float4*)&xs[srow][sk8 + 4] = v1;
        *(short8*)&ws[wcol][wk]     = *(const short8*)&Wt[(size_t)wcol * 128 + kt + wk];
        *(short8*)&ws[wcol][wk + 8] = *(const short8*)&Wt[(size_t)wcol * 128 + kt + wk + 8];
        if (emit) {
            float f[8] = {v0.x, v0.y, v0.z, v0.w, v1.x, v1.y, v1.z, v1.w};
            short8 hv;
#pragma unroll
            for (int i = 0; i < 8; ++i) {
                hv[i] = (short)f2bf(f[i]);
                sq = fmaf(f[i], f[i], sq);
            }
            *(short8*)&xh[(size_t)(r0 + srow) * 128 + kt + sk8] = hv;
        }
        __syncthreads();

        int arow = w * 16 + ln;
        f32x4 a0 = *(const f32x4*)&xs[arow][lg * 8];
        f32x4 a1 = *(const f32x4*)&xs[arow][lg * 8 + 4];
        float af[8] = {a0[0], a0[1], a0[2], a0[3], a1[0], a1[1], a1[2], a1[3]};
        short8 ah, al;
#pragma unroll
        for (int i = 0; i < 8; ++i) {
            unsigned short h = f2bf(af[i]);
            ah[i] = (short)h;
            float hf = __uint_as_float(((unsigned)h) << 16);
            al[i] = (short)f2bf(af[i] - hf);
        }
#pragma unroll
        for (int ct = 0; ct < 8; ++ct) {
            short8 bw = *(const short8*)&ws[ct * 16 + ln][lg * 8];
            acc[ct] = __builtin_amdgcn_mfma_f32_16x16x32_bf16(ah, bw, acc[ct], 0, 0, 0);
            acc[ct] = __builtin_amdgcn_mfma_f32_16x16x32_bf16(al, bw, acc[ct], 0, 0, 0);
        }
    }

    if (emit) {
        sq += __shfl_xor(sq, 1);
        sq += __shfl_xor(sq, 2);
        if ((tid & 3) == 0) sqn[r0 + srow] = sq;
    }

#pragma unroll
    for (int ct = 0; ct < 8; ++ct) {
        int c = ct * 16 + ln;
        float bv = bias[c];
#pragma unroll
        for (int rg = 0; rg < 4; ++rg) {
            int r = r0 + w * 16 + lg * 4 + rg;
            out[(size_t)r * 128 + c] = acc[ct][rg] + bv;
        }
    }
}

// ---------------------------------------------------------------- fused tail: fused -> FFN1 -> FFN2 -> out
__global__ __launch_bounds__(256) void tail_mfma_k(
    const float* __restrict__ ch2, const float* __restrict__ x,
    const unsigned short* __restrict__ wtc,
    const unsigned short* __restrict__ wtf1,
    const unsigned short* __restrict__ wtf2,
    const float* __restrict__ b_c, const float* __restrict__ b_f1,
    const float* __restrict__ b_f2, float* __restrict__ out)
{
    __shared__ char lds[60928];
    float* fused_s = (float*)lds;                              // [64][132] f32
    unsigned short* hid_s = (unsigned short*)(lds + 33792);    // [64][132] ushort
    float* xs = (float*)(lds + 33792);                         // [64][36] alias (phase A only)
    unsigned short* ws = (unsigned short*)(lds + 33792 + 16896); // [128][40] ushort

    int tid = threadIdx.x;
    int w = tid >> 6, lane = tid & 63;
    int lg = lane >> 4, ln = lane & 15;
    int r0 = blockIdx.x * 64;
    int srow = tid >> 2, sk8 = (tid & 3) * 8;
    int wcol = tid >> 1, wk = (tid & 1) * 16;
    int arow = w * 16 + ln;

    // ---- phase A: fused = ch2 @ wtc + b_c + x  (K=256)
    f32x4 acc[8];
#pragma unroll
    for (int ct = 0; ct < 8; ++ct) acc[ct] = {0.f, 0.f, 0.f, 0.f};
    for (int kt = 0; kt < 256; kt += 32) {
        __syncthreads();
        *(float4*)&xs[srow * 36 + sk8]     = *(const float4*)&ch2[(size_t)(r0 + srow) * 256 + kt + sk8];
        *(float4*)&xs[srow * 36 + sk8 + 4] = *(const float4*)&ch2[(size_t)(r0 + srow) * 256 + kt + sk8 + 4];
        *(short8*)&ws[wcol * 40 + wk]     = *(const short8*)&wtc[(size_t)wcol * 256 + kt + wk];
        *(short8*)&ws[wcol * 40 + wk + 8] = *(const short8*)&wtc[(size_t)wcol * 256 + kt + wk + 8];
        __syncthreads();
        f32x4 a0 = *(const f32x4*)&xs[arow * 36 + lg * 8];
        f32x4 a1 = *(const f32x4*)&xs[arow * 36 + lg * 8 + 4];
        float af[8] = {a0[0], a0[1], a0[2], a0[3], a1[0], a1[1], a1[2], a1[3]};
        short8 ah, al;
#pragma unroll
        for (int i = 0; i < 8; ++i) {
            unsigned short h = f2bf(af[i]);
            ah[i] = (short)h;
            float hf = __uint_as_float(((unsigned)h) << 16);
            al[i] = (short)f2bf(af[i] - hf);
        }
#pragma unroll
        for (int ct = 0; ct < 8; ++ct) {
            short8 bw = *(const short8*)&ws[(ct * 16 + ln) * 40 + lg * 8];
            acc[ct] = __builtin_amdgcn_mfma_f32_16x16x32_bf16(ah, bw, acc[ct], 0, 0, 0);
            acc[ct] = __builtin_amdgcn_mfma_f32_16x16x32_bf16(al, bw, acc[ct], 0, 0, 0);
        }
    }
    __syncthreads();
#pragma unroll
    for (int ct = 0; ct < 8; ++ct) {
        int c = ct * 16 + ln;
        float bv = b_c[c];
#pragma unroll
        for (int rg = 0; rg < 4; ++rg) {
            int r = w * 16 + lg * 4 + rg;
            fused_s[r * 132 + c] = acc[ct][rg] + bv + x[(size_t)(r0 + r) * 128 + c];
        }
    }
    __syncthreads();

    // ---- FFN halves
    f32x4 acc2[8];
#pragma unroll
    for (int ct = 0; ct < 8; ++ct) acc2[ct] = {0.f, 0.f, 0.f, 0.f};

    for (int hh = 0; hh < 2; ++hh) {
        f32x4 acc1[8];
#pragma unroll
        for (int ct = 0; ct < 8; ++ct) acc1[ct] = {0.f, 0.f, 0.f, 0.f};
        for (int kt = 0; kt < 128; kt += 32) {
            __syncthreads();
            *(short8*)&ws[wcol * 40 + wk]     = *(const short8*)&wtf1[(size_t)(hh * 128 + wcol) * 128 + kt + wk];
            *(short8*)&ws[wcol * 40 + wk + 8] = *(const short8*)&wtf1[(size_t)(hh * 128 + wcol) * 128 + kt + wk + 8];
            __syncthreads();
            f32x4 a0 = *(const f32x4*)&fused_s[arow * 132 + kt + lg * 8];
            f32x4 a1 = *(const f32x4*)&fused_s[arow * 132 + kt + lg * 8 + 4];
            float af[8] = {a0[0], a0[1], a0[2], a0[3], a1[0], a1[1], a1[2], a1[3]};
            short8 ah, al;
#pragma unroll
            for (int i = 0; i < 8; ++i) {
                unsigned short h = f2bf(af[i]);
                ah[i] = (short)h;
                float hf = __uint_as_float(((unsigned)h) << 16);
                al[i] = (short)f2bf(af[i] - hf);
            }
#pragma unroll
            for (int ct = 0; ct < 8; ++ct) {
                short8 bw = *(const short8*)&ws[(ct * 16 + ln) * 40 + lg * 8];
                acc1[ct] = __builtin_amdgcn_mfma_f32_16x16x32_bf16(ah, bw, acc1[ct], 0, 0, 0);
                acc1[ct] = __builtin_amdgcn_mfma_f32_16x16x32_bf16(al, bw, acc1[ct], 0, 0, 0);
            }
        }
        __syncthreads();
#pragma unroll
        for (int ct = 0; ct < 8; ++ct) {
            int c = ct * 16 + ln;
            float bv = b_f1[hh * 128 + c];
#pragma unroll
            for (int rg = 0; rg < 4; ++rg) {
                int r = w * 16 + lg * 4 + rg;
                float hv = fminf(fmaxf(acc1[ct][rg] + bv, 0.f), 6.f);
                hid_s[r * 132 + c] = f2bf(hv);
            }
        }
        __syncthreads();

        for (int kt = 0; kt < 128; kt += 32) {
            __syncthreads();
            *(short8*)&ws[wcol * 40 + wk]     = *(const short8*)&wtf2[(size_t)wcol * 256 + hh * 128 + kt + wk];
            *(short8*)&ws[wcol * 40 + wk + 8] = *(const short8*)&wtf2[(size_t)wcol * 256 + hh * 128 + kt + wk + 8];
            __syncthreads();
            short8 ah = *(const short8*)&hid_s[arow * 132 + kt + lg * 8];
#pragma unroll
            for (int ct = 0; ct < 8; ++ct) {
                short8 bw = *(const short8*)&ws[(ct * 16 + ln) * 40 + lg * 8];
                acc2[ct] = __builtin_amdgcn_mfma_f32_16x16x32_bf16(ah, bw, acc2[ct], 0, 0, 0);
            }
        }
    }

#pragma unroll
    for (int ct = 0; ct < 8; ++ct) {
        int c = ct * 16 + ln;
        float bv = b_f2[c];
#pragma unroll
        for (int rg = 0; rg < 4; ++rg) {
            int r = w * 16 + lg * 4 + rg;
            float v = acc2[ct][rg] + bv + fused_s[r * 132 + c];
            out[(size_t)(r0 + r) * 128 + c] = fminf(fmaxf(v, 0.f), 6.f);
        }
    }
}

// ---------------------------------------------------------------- branchless sorted insert (ascending u32)
__device__ __forceinline__ void ins6(unsigned (&d)[6], unsigned k)
{
#pragma unroll
    for (int t = 0; t < 6; ++t) {
        unsigned lo = d[t] < k ? d[t] : k;
        unsigned hi = d[t] < k ? k : d[t];
        d[t] = lo; k = hi;
    }
}

// ---------------------------------------------------------------- kNN prefilter via MFMA (R11 config, frozen)
__global__ __launch_bounds__(256) void knn_mfma_k(const unsigned short* __restrict__ xh,
                                                  const float* __restrict__ sqn,
                                                  int* __restrict__ cand)
{
    __shared__ char lds[16640];               // 16KB hi tile + 256B biased csq
    char* ldsH = lds;
    float* cs_s = (float*)(lds + 16384);

    int b = blockIdx.x;
    int g = b & 7, r = b >> 3;                // g == XCD id -> per-graph L2 locality
    int chunk = r & 7, qblk = r >> 3;
    int gbase = g * Sg;
    int cbase = chunk * CLEN;
    int qlen = (chunk < 7) ? CLEN : (Sg - 7 * CLEN);  // 520 last
    int ntiles = (qlen + 63) >> 6;                     // 10 or 9
    int nfull = (chunk < 7) ? ntiles : ntiles - 1;
    int tid = threadIdx.x;
    int w = tid >> 6, lane = tid & 63;
    int lg = lane >> 4, ln = lane & 15;
    int q0 = qblk * 128 + w * 32;

    short8 bh[2][4];
#pragma unroll
    for (int s = 0; s < 2; ++s) {
        int q = q0 + s * 16 + ln;
        int qrow = gbase + (q < Sg ? q : Sg - 1);
#pragma unroll
        for (int ks = 0; ks < 4; ++ks)
            bh[s][ks] = *(const short8*)&xh[(size_t)qrow * 128 + ks * 32 + lg * 8];
    }

    int srow = tid >> 4, sslot = tid & 15;
    int sw_st = (srow & 7) << 4;
    int dstoff[4];
    const unsigned short* src[4];
#pragma unroll
    for (int i = 0; i < 4; ++i) {
        int row = i * 16 + srow;
        dstoff[i] = row * 256 + ((sslot * 16) ^ sw_st);
        src[i] = &xh[(size_t)(gbase + cbase + row) * 128 + sslot * 8];
    }
    const float* csrc = &sqn[gbase + cbase];

    unsigned d6a[6], d6b[6];
#pragma unroll
    for (int t = 0; t < 6; ++t) { d6a[t] = 0xFFFFFFFFu; d6b[t] = 0xFFFFFFFFu; }

    for (int t64 = 0; t64 < ntiles; ++t64) {
        __syncthreads();
        if (t64 < nfull) {
#pragma unroll
            for (int i = 0; i < 4; ++i) {
                short8 vh = *(const short8*)src[i];
                src[i] += 64 * 128;
                *(short8*)(ldsH + dstoff[i]) = vh;
            }
            if (tid < 64) cs_s[tid] = csrc[tid] + 1024.0f;
        } else {
            int c0 = cbase + t64 * 64;
#pragma unroll
            for (int i = 0; i < 4; ++i) {
                int cr = c0 + i * 16 + srow;
                if (cr >= Sg) cr = Sg - 1;
                short8 vh = *(const short8*)&xh[(size_t)(gbase + cr) * 128 + sslot * 8];
                *(short8*)(ldsH + dstoff[i]) = vh;
            }
            if (tid < 64) {
                int cl = c0 + tid;
                cs_s[tid] = (cl < cbase + qlen) ? (sqn[gbase + cl] + 1024.0f) : __builtin_inff();
            }
        }
        csrc += 64;
        __syncthreads();

        int c0 = cbase + t64 * 64;
#pragma unroll
        for (int g16 = 0; g16 < 4; ++g16) {
            f32x4 acc0 = {0.f, 0.f, 0.f, 0.f};
            f32x4 acc1 = {0.f, 0.f, 0.f, 0.f};
            int rr = g16 * 16 + ln;
            int rsw = (ln & 7) << 4;
#pragma unroll
            for (int ks = 0; ks < 4; ++ks) {
                short8 ah = *(const short8*)(ldsH + rr * 256 + ((lg * 16 + ks * 64) ^ rsw));
                acc0 = __builtin_amdgcn_mfma_f32_16x16x32_bf16(ah, bh[0][ks], acc0, 0, 0, 0);
                acc1 = __builtin_amdgcn_mfma_f32_16x16x32_bf16(ah, bh[1][ks], acc1, 0, 0, 0);
            }
            f32x4 cv = *(const f32x4*)&cs_s[g16 * 16 + lg * 4];
            int idx0 = (c0 - cbase) + g16 * 16 + lg * 4;
#pragma unroll
            for (int rg = 0; rg < 4; ++rg) {
                unsigned ki = (unsigned)(idx0 + rg);
                unsigned k0 = (__float_as_uint(fmaf(-2.f, acc0[rg], cv[rg])) & 0xFFFFF800u) | ki;
                unsigned k1 = (__float_as_uint(fmaf(-2.f, acc1[rg], cv[rg])) & 0xFFFFF800u) | ki;
                ins6(d6a, k0);
                ins6(d6b, k1);
            }
        }
    }

#pragma unroll
    for (int s = 0; s < 2; ++s) {
        unsigned m6[6];
#pragma unroll
        for (int t = 0; t < 6; ++t) m6[t] = s ? d6b[t] : d6a[t];
#pragma unroll
        for (int sg = 1; sg < 4; ++sg)
#pragma unroll
            for (int t = 0; t < 6; ++t) {
                unsigned v = __shfl(s ? d6b[t] : d6a[t], ln + sg * 16);
#pragma unroll
                for (int u = 0; u < 6; ++u) {
                    unsigned lo = m6[u] < v ? m6[u] : v;
                    unsigned hi = m6[u] < v ? v : m6[u];
                    m6[u] = lo; v = hi;
                }
            }
        int q = q0 + s * 16 + ln;
        if (lg == 0 && q < Sg) {
            int* cp = &cand[(size_t)(gbase + q) * NCAND + chunk * 6];
#pragma unroll
            for (int t = 0; t < 6; ++t) cp[t] = gbase + cbase + (int)(m6[t] & 2047u);
        }
    }
}

// ---------------------------------------------------------------- exact fp32 re-rank, wave per query (linear map)
__global__ __launch_bounds__(256) void knn_rerank_k(const float* __restrict__ x,
                                                    const float* __restrict__ sqn,
                                                    const int* __restrict__ cand,
                                                    int* __restrict__ knn_idx)
{
    int w = threadIdx.x >> 6, lane = threadIdx.x & 63;
    int grp = lane >> 4, gl = lane & 15;
    int q = blockIdx.x * 4 + w;
    float4 qa = *(const float4*)&x[(size_t)q * 128 + gl * 8];
    float4 qb = *(const float4*)&x[(size_t)q * 128 + gl * 8 + 4];
    const int* cp = &cand[(size_t)q * NCAND + grp * 12];

    int ca[12]; unsigned okm = 0;
#pragma unroll
    for (int j = 0; j < 12; ++j) {
        int c = cp[j];
        bool ok = (unsigned)c < (unsigned)N && c != q;
        okm |= (ok ? 1u : 0u) << j;
        ca[j] = ok ? c : 0;
    }

    float d6[6]; int i6[6]; float mx = __builtin_inff(); int sl = 0;
#pragma unroll
    for (int t = 0; t < 6; ++t) { d6[t] = __builtin_inff(); i6[t] = -1; }

    float4 vaA = *(const float4*)&x[(size_t)ca[0] * 128 + gl * 8];
    float4 vbA = *(const float4*)&x[(size_t)ca[0] * 128 + gl * 8 + 4];
#pragma unroll
    for (int j = 0; j < 12; ++j) {
        float4 vaB, vbB;
        if (j < 11) {
            vaB = *(const float4*)&x[(size_t)ca[j + 1] * 128 + gl * 8];
            vbB = *(const float4*)&x[(size_t)ca[j + 1] * 128 + gl * 8 + 4];
        }
        float p = qa.x * vaA.x;
        p = fmaf(qa.y, vaA.y, p); p = fmaf(qa.z, vaA.z, p); p = fmaf(qa.w, vaA.w, p);
        p = fmaf(qb.x, vbA.x, p); p = fmaf(qb.y, vbA.y, p);
        p = fmaf(qb.z, vbA.z, p); p = fmaf(qb.w, vbA.w, p);
#pragma unroll
        for (int off = 1; off < 16; off <<= 1) p += __shfl_xor(p, off);
        float dv = ((okm >> j) & 1u) ? fmaf(-2.f, p, sqn[ca[j]]) : __builtin_inff();
        if (dv < mx) {
#pragma unroll
            for (int t = 0; t < 6; ++t)
                if (t == sl) { d6[t] = dv; i6[t] = ca[j]; }
            float m2 = d6[0]; int s2 = 0;
#pragma unroll
            for (int t = 1; t < 6; ++t)
                if (d6[t] > m2) { m2 = d6[t]; s2 = t; }
            mx = m2; sl = s2;
        }
        vaA = vaB; vbA = vbB;
    }

#pragma unroll
    for (int sg = 1; sg < 4; ++sg) {
#pragma unroll
        for (int t = 0; t < 6; ++t) {
            float dv = __shfl(d6[t], gl + sg * 16);
            int ci = __shfl(i6[t], gl + sg * 16);
            if (grp == 0 && dv < mx) {
#pragma unroll
                for (int u = 0; u < 6; ++u)
                    if (u == sl) { d6[u] = dv; i6[u] = ci; }
                float m2 = d6[0]; int s2 = 0;
#pragma unroll
                for (int u = 1; u < 6; ++u)
                    if (d6[u] > m2) { m2 = d6[u]; s2 = u; }
                mx = m2; sl = s2;
            }
        }
    }
    if (lane < 6) {
        int v;
#pragma unroll
        for (int t = 0; t < 6; ++t) if (t == lane) v = i6[t];
        knn_idx[(size_t)q * 6 + lane] = v;
    }
}

// ---------------------------------------------------------------- CSR build
__global__ __launch_bounds__(256) void hist_k(const int* __restrict__ dstA, int* __restrict__ deg)
{
    int e = blockIdx.x * 256 + threadIdx.x;
    atomicAdd(&deg[dstA[e]], 1);
}

__global__ __launch_bounds__(1024) void scan_k(const int* __restrict__ deg, int* __restrict__ rowptr,
                                               int* __restrict__ cnt)
{
    __shared__ int ps[1024];
    int t = threadIdx.x;
    const int chunk = 40;
    int base = t * chunk;
    int s = 0;
    for (int k = 0; k < chunk; ++k) {
        int i = base + k;
        if (i < N) { s += deg[i]; cnt[i] = 0; }   // fold cnt memset
    }
    ps[t] = s;
    __syncthreads();
    for (int off = 1; off < 1024; off <<= 1) {
        int v = (t >= off) ? ps[t - off] : 0;
        __syncthreads();
        ps[t] += v;
        __syncthreads();
    }
    int run = ps[t] - s;
    for (int k = 0; k < chunk; ++k) {
        int i = base + k;
        if (i < N) { rowptr[i] = run; run += deg[i]; }
    }
    if (t == 0) rowptr[N] = E;
}

__global__ __launch_bounds__(256) void scatter_k(const int* __restrict__ srcA, const int* __restrict__ dstA,
                                                 const float* __restrict__ ea,
                                                 const int* __restrict__ rowptr, int* __restrict__ cnt,
                                                 int* __restrict__ csr_src, float* __restrict__ csr_ea)
{
    int e = blockIdx.x * 256 + threadIdx.x;
    int d = dstA[e];
    int pos = rowptr[d] + atomicAdd(&cnt[d], 1);
    csr_src[pos] = srcA[e];
    csr_ea[pos] = ea[e];
}

// ---------------------------------------------------------------- fused GAT (blockIdx.y: 0=spatial, 1=latent; linear map)
__global__ __launch_bounds__(256) void gat_fused_k(
    const float* __restrict__ xl_s, const float* __restrict__ xr_s,
    const int* __restrict__ rowptr, const int* __restrict__ csr_src, const float* __restrict__ csr_ea,
    const float* __restrict__ att_s, const float* __restrict__ wse, const float* __restrict__ bias_s,
    const float* __restrict__ xl_l, const float* __restrict__ xr_l,
    const int* __restrict__ knn, const float* __restrict__ att_l, const float* __restrict__ bias_l,
    float* __restrict__ ch2)
{
    int w = threadIdx.x >> 6, lane = threadIdx.x & 63;
    int dst = blockIdx.x * 4 + w;

    if (blockIdx.y == 0) {
        int base = rowptr[dst];
        int deg = rowptr[dst + 1] - base;
        float xr0 = xr_s[(size_t)dst * 128 + lane], xr1 = xr_s[(size_t)dst * 128 + 64 + lane];
        float at0 = att_s[lane], at1 = att_s[64 + lane];
        float we0 = wse[lane], we1 = wse[64 + lane];

        float eaN = 0.f, v0N = 0.f, v1N = 0.f;
        if (deg > 0) {
            int s0 = csr_src[base];
            eaN = csr_ea[base];
            v0N = xl_s[(size_t)s0 * 128 + lane];
            v1N = xl_s[(size_t)s0 * 128 + 64 + lane];
        }
        float m = -1e30f, ssum = 0.f, o0 = 0.f, o1 = 0.f;
        for (int i = 0; i < deg; ++i) {
            float ea = eaN, v0 = v0N, v1 = v1N;
            if (i + 1 < deg) {
                int sn = csr_src[base + i + 1];
                eaN = csr_ea[base + i + 1];
                v0N = xl_s[(size_t)sn * 128 + lane];
                v1N = xl_s[(size_t)sn * 128 + 64 + lane];
            }
            float h0 = fmaf(ea, we0, v0 + xr0);
            float h1 = fmaf(ea, we1, v1 + xr1);
            h0 = h0 > 0.f ? h0 : 0.2f * h0;
            h1 = h1 > 0.f ? h1 : 0.2f * h1;
            float p = fmaf(h1, at1, h0 * at0);
#pragma unroll
            for (int off = 32; off; off >>= 1) p += __shfl_xor(p, off);
            if (p <= m) {
                float wt = __expf(p - m);
                ssum += wt;
                o0 = fmaf(wt, v0, o0);
                o1 = fmaf(wt, v1, o1);
            } else {
                float sc = __expf(m - p);
                ssum = fmaf(ssum, sc, 1.f);
                o0 = fmaf(o0, sc, v0);
                o1 = fmaf(o1, sc, v1);
                m = p;
            }
        }
        float inv = deg > 0 ? 1.f / ssum : 0.f;
        ch2[(size_t)dst * 256 + lane]      = fmaf(o0, inv, bias_s[lane]);
        ch2[(size_t)dst * 256 + 64 + lane] = fmaf(o1, inv, bias_s[64 + lane]);
    } else {
        float xr0 = xr_l[(size_t)dst * 128 + lane], xr1 = xr_l[(size_t)dst * 128 + 64 + lane];
        float at0 = att_l[lane], at1 = att_l[64 + lane];
        int s[7];
#pragma unroll
        for (int j = 0; j < 6; ++j) s[j] = knn[(size_t)dst * 6 + j];
        s[6] = dst;
        float l[7];
#pragma unroll
        for (int j = 0; j < 7; ++j) {
            float h0 = xl_l[(size_t)s[j] * 128 + lane] + xr0;
            float h1 = xl_l[(size_t)s[j] * 128 + 64 + lane] + xr1;
            h0 = h0 > 0.f ? h0 : 0.2f * h0;
            h1 = h1 > 0.f ? h1 : 0.2f * h1;
            float p = h0 * at0 + h1 * at1;
#pragma unroll
            for (int off = 32; off; off >>= 1) p += __shfl_xor(p, off);
            l[j] = p;
        }
        float m = l[0];
#pragma unroll
        for (int j = 1; j < 7; ++j) m = fmaxf(m, l[j]);
        float sum = 0.f;
#pragma unroll
        for (int j = 0; j < 7; ++j) { l[j] = __expf(l[j] - m); sum += l[j]; }
        float inv = 1.f / sum;
        float o0 = 0.f, o1 = 0.f;
#pragma unroll
        for (int j = 0; j < 7; ++j) {
            float a = l[j] * inv;
            o0 = fmaf(a, xl_l[(size_t)s[j] * 128 + lane], o0);
            o1 = fmaf(a, xl_l[(size_t)s[j] * 128 + 64 + lane], o1);
        }
        ch2[(size_t)dst * 256 + 128 + lane] = o0 + bias_l[lane];
        ch2[(size_t)dst * 256 + 192 + lane] = o1 + bias_l[64 + lane];
    }
}

// ---------------------------------------------------------------- launch
extern "C" void kernel_launch(void* const* d_in, const int* in_sizes, int n_in,
                              void* d_out, int out_size, void* d_ws, size_t ws_size,
                              hipStream_t stream)
{
    const float* x      = (const float*)d_in[0];
    const int*   ei     = (const int*)  d_in[1];
    const float* eattr  = (const float*)d_in[2];
    const float* W_sl   = (const float*)d_in[4];
    const float* b_sl   = (const float*)d_in[5];
    const float* W_sr   = (const float*)d_in[6];
    const float* b_sr   = (const float*)d_in[7];
    const float* att_s  = (const float*)d_in[8];
    const float* W_se   = (const float*)d_in[9];
    const float* bias_s = (const float*)d_in[10];
    const float* W_ll   = (const float*)d_in[11];
    const float* b_ll   = (const float*)d_in[12];
    const float* W_lr   = (const float*)d_in[13];
    const float* b_lr   = (const float*)d_in[14];
    const float* att_l  = (const float*)d_in[15];
    const float* bias_l = (const float*)d_in[16];
    const float* W_c    = (const float*)d_in[17];
    const float* b_c    = (const float*)d_in[18];
    const float* W_f1   = (const float*)d_in[19];
    const float* b_f1   = (const float*)d_in[20];
    const float* W_f2   = (const float*)d_in[21];
    const float* b_f2   = (const float*)d_in[22];
    float* out = (float*)d_out;

    char* wp = (char*)d_ws;
    auto take = [&](size_t bytes) { char* p = wp; wp += (bytes + 255) & ~(size_t)255; return p; };
    float* xl_s    = (float*)take((size_t)N * D * 4);
    float* xr_s    = (float*)take((size_t)N * D * 4);
    float* xl_l    = (float*)take((size_t)N * D * 4);
    float* xr_l    = (float*)take((size_t)N * D * 4);
    float* ch2     = (float*)take((size_t)N * 2 * D * 4);
    float* sqn     = (float*)take((size_t)N * 4);
    int*   knn_idx = (int*)  take((size_t)N * KN * 4);
    int*   deg     = (int*)  take((size_t)N * 4);
    int*   cnt     = (int*)  take((size_t)N * 4);
    int*   rowptr  = (int*)  take((size_t)(N + 1) * 4);
    int*   csr_src = (int*)  take((size_t)E * 4);
    float* csr_ea  = (float*)take((size_t)E * 4);
    unsigned short* x_hi = (unsigned short*)take((size_t)N * D * 2);
    int*   knn_cand = (int*)take((size_t)N * NCAND * 4);
    unsigned short* wt4  = (unsigned short*)take(65536 * 2);
    unsigned short* wtc  = (unsigned short*)take(32768 * 2);
    unsigned short* wtf1 = (unsigned short*)take(32768 * 2);
    unsigned short* wtf2 = (unsigned short*)take(32768 * 2);
    if ((size_t)(wp - (char*)d_ws) > ws_size) return;

    dim3 blk(256);

    // weight transpose + bf16 cast + deg zero (one-shot)
    w_prep_k<<<dim3(640), blk, 0, stream>>>(W_sl, W_sr, W_ll, W_lr, W_c, W_f1, W_f2,
                                            wt4, wtc, wtf1, wtf2, deg);

    // fused node transforms (4 outputs) + xh/sqn prep folded into y==0 blocks
    gemm4_mfma_k<<<dim3(N / 64, 4), blk, 0, stream>>>(x, wt4,
        b_sl, b_sr, b_ll, b_lr, xl_s, xr_s, xl_l, xr_l, x_hi, sqn);

    // kNN graph: bf16 MFMA prefilter (8 chunks) -> exact fp32 re-rank
    knn_mfma_k<<<dim3(Bg * 40 * 8), blk, 0, stream>>>(x_hi, sqn, knn_cand);
    knn_rerank_k<<<dim3(N / 4), blk, 0, stream>>>(x, sqn, knn_cand, knn_idx);

    // CSR of spatial edges by dst (cnt zeroed inside scan_k)
    hist_k<<<dim3(E / 256), blk, 0, stream>>>(ei + E, deg);
    scan_k<<<dim3(1), dim3(1024), 0, stream>>>(deg, rowptr, cnt);
    scatter_k<<<dim3(E / 256), blk, 0, stream>>>(ei, ei + E, eattr, rowptr, cnt, csr_src, csr_ea);

    // both GAT channels in one launch -> ch2 = [ch_sp | ch_lat]
    gat_fused_k<<<dim3(N / 4, 2), blk, 0, stream>>>(xl_s, xr_s, rowptr, csr_src, csr_ea,
                                                    att_s, W_se, bias_s,
                                                    xl_l, xr_l, knn_idx, att_l, bias_l, ch2);

    // fused tail: fusion + FFN1 + FFN2 in one kernel (no HBM intermediates)
    tail_mfma_k<<<dim3(N / 64), blk, 0, stream>>>(ch2, x, wtc, wtf1, wtf2,
                                                  b_c, b_f1, b_f2, out);
}

// Round 16
// 486.337 us; speedup vs baseline: 1.0782x; 1.0782x over previous
//
#include <hip/hip_runtime.h>
#include <math.h>

// ---------------------------------------------------------------- constants
constexpr int N  = 40000;   // nodes
constexpr int D  = 128;     // latent dim
constexpr int E  = 640000;  // spatial edges
constexpr int Bg = 8;       // graphs
constexpr int Sg = 5000;    // nodes per graph
constexpr int KN = 6;       // knn
constexpr int FF = 256;     // ffn hidden
constexpr int CLEN = 640;   // candidate chunk length (64-aligned); chunk 7 = 520
constexpr int NCAND = 48;   // 8 chunks x top-6

typedef short short8 __attribute__((ext_vector_type(8)));
typedef float f32x4  __attribute__((ext_vector_type(4)));

// ---------------------------------------------------------------- bf16 helpers
__device__ __forceinline__ unsigned short f2bf(float f)
{
    unsigned int u = __float_as_uint(f);
    return (unsigned short)((u + 0x7fffu + ((u >> 16) & 1u)) >> 16);
}

// ---------------------------------------------------------------- W pre-transpose + bf16 cast (one-shot)
__global__ __launch_bounds__(256) void w_prep_k(
    const float* __restrict__ W0, const float* __restrict__ W1,
    const float* __restrict__ W2, const float* __restrict__ W3,
    const float* __restrict__ Wc, const float* __restrict__ Wf1,
    const float* __restrict__ Wf2,
    unsigned short* __restrict__ wt4, unsigned short* __restrict__ wtc,
    unsigned short* __restrict__ wtf1, unsigned short* __restrict__ wtf2)
{
    int idx = blockIdx.x * 256 + threadIdx.x;
    if (idx < 65536) {                        // node transforms [128][128]
        int m = idx >> 14, rem = idx & 16383;
        int k = rem & 127, c = rem >> 7;
        const float* Wm = (m == 0) ? W0 : (m == 1) ? W1 : (m == 2) ? W2 : W3;
        wt4[m * 16384 + c * 128 + k] = f2bf(Wm[k * 128 + c]);
    } else if (idx < 98304) {                 // W_c [256][128] -> [128][256]
        int rem = idx - 65536; int k = rem & 255, c = rem >> 8;
        wtc[c * 256 + k] = f2bf(Wc[k * 128 + c]);
    } else if (idx < 131072) {                // W_f1 [128][256] -> [256][128]
        int rem = idx - 98304; int k = rem & 127, c = rem >> 7;
        wtf1[c * 128 + k] = f2bf(Wf1[k * 256 + c]);
    } else {                                  // W_f2 [256][128] -> [128][256]
        int rem = idx - 131072; int k = rem & 255, c = rem >> 8;
        wtf2[c * 256 + k] = f2bf(Wf2[k * 128 + c]);
    }
}

// ---------------------------------------------------------------- fused 4x node-transform MFMA GEMM
// blockIdx.y==0 blocks additionally emit xh (bf16 cast of x) and sqn (row norms).
__global__ __launch_bounds__(256) void gemm4_mfma_k(
    const float* __restrict__ A, const unsigned short* __restrict__ wt4,
    const float* __restrict__ b0, const float* __restrict__ b1,
    const float* __restrict__ b2, const float* __restrict__ b3,
    float* __restrict__ o0, float* __restrict__ o1,
    float* __restrict__ o2, float* __restrict__ o3,
    unsigned short* __restrict__ xh, float* __restrict__ sqn)
{
    const unsigned short* Wt = wt4 + blockIdx.y * 16384;
    const float* bias; float* out;
    if (blockIdx.y == 0)      { bias = b0; out = o0; }
    else if (blockIdx.y == 1) { bias = b1; out = o1; }
    else if (blockIdx.y == 2) { bias = b2; out = o2; }
    else                      { bias = b3; out = o3; }

    __shared__ float xs[64][36];
    __shared__ unsigned short ws[128][40];
    int tid = threadIdx.x;
    int w = tid >> 6, lane = tid & 63;
    int lg = lane >> 4, ln = lane & 15;
    int r0 = blockIdx.x * 64;

    f32x4 acc[8];
#pragma unroll
    for (int ct = 0; ct < 8; ++ct) acc[ct] = {0.f, 0.f, 0.f, 0.f};

    int srow = tid >> 2, sk8 = (tid & 3) * 8;
    int wcol = tid >> 1, wk = (tid & 1) * 16;
    bool emit = (blockIdx.y == 0);
    float sq = 0.f;

    for (int kt = 0; kt < 128; kt += 32) {
        __syncthreads();
        float4 v0 = *(const float4*)&A[(size_t)(r0 + srow) * 128 + kt + sk8];
        float4 v1 = *(const float4*)&A[(size_t)(r0 + srow) * 128 + kt + sk8 + 4];
        *(float4*)&xs[srow][sk8]     = v0;
        *(float4*)&xs[srow][sk8 + 4] = v1;
        *(short8*)&ws[wcol][wk]     = *(const short8*)&Wt[(size_t)wcol * 128 + kt + wk];
        *(short8*)&ws[wcol][wk + 8] = *(const short8*)&Wt[(size_t)wcol * 128 + kt + wk + 8];
        if (emit) {
            float f[8] = {v0.x, v0.y, v0.z, v0.w, v1.x, v1.y, v1.z, v1.w};
            short8 hv;
#pragma unroll
            for (int i = 0; i < 8; ++i) {
                hv[i] = (short)f2bf(f[i]);
                sq = fmaf(f[i], f[i], sq);
            }
            *(short8*)&xh[(size_t)(r0 + srow) * 128 + kt + sk8] = hv;
        }
        __syncthreads();

        int arow = w * 16 + ln;
        f32x4 a0 = *(const f32x4*)&xs[arow][lg * 8];
        f32x4 a1 = *(const f32x4*)&xs[arow][lg * 8 + 4];
        float af[8] = {a0[0], a0[1], a0[2], a0[3], a1[0], a1[1], a1[2], a1[3]};
        short8 ah, al;
#pragma unroll
        for (int i = 0; i < 8; ++i) {
            unsigned short h = f2bf(af[i]);
            ah[i] = (short)h;
            float hf = __uint_as_float(((unsigned)h) << 16);
            al[i] = (short)f2bf(af[i] - hf);
        }
#pragma unroll
        for (int ct = 0; ct < 8; ++ct) {
            short8 bw = *(const short8*)&ws[ct * 16 + ln][lg * 8];
            acc[ct] = __builtin_amdgcn_mfma_f32_16x16x32_bf16(ah, bw, acc[ct], 0, 0, 0);
            acc[ct] = __builtin_amdgcn_mfma_f32_16x16x32_bf16(al, bw, acc[ct], 0, 0, 0);
        }
    }

    if (emit) {
        sq += __shfl_xor(sq, 1);
        sq += __shfl_xor(sq, 2);
        if ((tid & 3) == 0) sqn[r0 + srow] = sq;
    }

#pragma unroll
    for (int ct = 0; ct < 8; ++ct) {
        int c = ct * 16 + ln;
        float bv = bias[c];
#pragma unroll
        for (int rg = 0; rg < 4; ++rg) {
            int r = r0 + w * 16 + lg * 4 + rg;
            out[(size_t)r * 128 + c] = acc[ct][rg] + bv;
        }
    }
}

// ---------------------------------------------------------------- fused tail: fused -> FFN1 -> FFN2 -> out
__global__ __launch_bounds__(256) void tail_mfma_k(
    const float* __restrict__ ch2, const float* __restrict__ x,
    const unsigned short* __restrict__ wtc,
    const unsigned short* __restrict__ wtf1,
    const unsigned short* __restrict__ wtf2,
    const float* __restrict__ b_c, const float* __restrict__ b_f1,
    const float* __restrict__ b_f2, float* __restrict__ out)
{
    __shared__ char lds[60928];
    float* fused_s = (float*)lds;                              // [64][132] f32
    unsigned short* hid_s = (unsigned short*)(lds + 33792);    // [64][132] ushort
    float* xs = (float*)(lds + 33792);                         // [64][36] alias (phase A only)
    unsigned short* ws = (unsigned short*)(lds + 33792 + 16896); // [128][40] ushort

    int tid = threadIdx.x;
    int w = tid >> 6, lane = tid & 63;
    int lg = lane >> 4, ln = lane & 15;
    int r0 = blockIdx.x * 64;
    int srow = tid >> 2, sk8 = (tid & 3) * 8;
    int wcol = tid >> 1, wk = (tid & 1) * 16;
    int arow = w * 16 + ln;

    // ---- phase A: fused = ch2 @ wtc + b_c + x  (K=256)
    f32x4 acc[8];
#pragma unroll
    for (int ct = 0; ct < 8; ++ct) acc[ct] = {0.f, 0.f, 0.f, 0.f};
    for (int kt = 0; kt < 256; kt += 32) {
        __syncthreads();
        *(float4*)&xs[srow * 36 + sk8]     = *(const float4*)&ch2[(size_t)(r0 + srow) * 256 + kt + sk8];
        *(float4*)&xs[srow * 36 + sk8 + 4] = *(const float4*)&ch2[(size_t)(r0 + srow) * 256 + kt + sk8 + 4];
        *(short8*)&ws[wcol * 40 + wk]     = *(const short8*)&wtc[(size_t)wcol * 256 + kt + wk];
        *(short8*)&ws[wcol * 40 + wk + 8] = *(const short8*)&wtc[(size_t)wcol * 256 + kt + wk + 8];
        __syncthreads();
        f32x4 a0 = *(const f32x4*)&xs[arow * 36 + lg * 8];
        f32x4 a1 = *(const f32x4*)&xs[arow * 36 + lg * 8 + 4];
        float af[8] = {a0[0], a0[1], a0[2], a0[3], a1[0], a1[1], a1[2], a1[3]};
        short8 ah, al;
#pragma unroll
        for (int i = 0; i < 8; ++i) {
            unsigned short h = f2bf(af[i]);
            ah[i] = (short)h;
            float hf = __uint_as_float(((unsigned)h) << 16);
            al[i] = (short)f2bf(af[i] - hf);
        }
#pragma unroll
        for (int ct = 0; ct < 8; ++ct) {
            short8 bw = *(const short8*)&ws[(ct * 16 + ln) * 40 + lg * 8];
            acc[ct] = __builtin_amdgcn_mfma_f32_16x16x32_bf16(ah, bw, acc[ct], 0, 0, 0);
            acc[ct] = __builtin_amdgcn_mfma_f32_16x16x32_bf16(al, bw, acc[ct], 0, 0, 0);
        }
    }
    __syncthreads();
#pragma unroll
    for (int ct = 0; ct < 8; ++ct) {
        int c = ct * 16 + ln;
        float bv = b_c[c];
#pragma unroll
        for (int rg = 0; rg < 4; ++rg) {
            int r = w * 16 + lg * 4 + rg;
            fused_s[r * 132 + c] = acc[ct][rg] + bv + x[(size_t)(r0 + r) * 128 + c];
        }
    }
    __syncthreads();

    // ---- FFN halves
    f32x4 acc2[8];
#pragma unroll
    for (int ct = 0; ct < 8; ++ct) acc2[ct] = {0.f, 0.f, 0.f, 0.f};

    for (int hh = 0; hh < 2; ++hh) {
        f32x4 acc1[8];
#pragma unroll
        for (int ct = 0; ct < 8; ++ct) acc1[ct] = {0.f, 0.f, 0.f, 0.f};
        for (int kt = 0; kt < 128; kt += 32) {
            __syncthreads();
            *(short8*)&ws[wcol * 40 + wk]     = *(const short8*)&wtf1[(size_t)(hh * 128 + wcol) * 128 + kt + wk];
            *(short8*)&ws[wcol * 40 + wk + 8] = *(const short8*)&wtf1[(size_t)(hh * 128 + wcol) * 128 + kt + wk + 8];
            __syncthreads();
            f32x4 a0 = *(const f32x4*)&fused_s[arow * 132 + kt + lg * 8];
            f32x4 a1 = *(const f32x4*)&fused_s[arow * 132 + kt + lg * 8 + 4];
            float af[8] = {a0[0], a0[1], a0[2], a0[3], a1[0], a1[1], a1[2], a1[3]};
            short8 ah, al;
#pragma unroll
            for (int i = 0; i < 8; ++i) {
                unsigned short h = f2bf(af[i]);
                ah[i] = (short)h;
                float hf = __uint_as_float(((unsigned)h) << 16);
                al[i] = (short)f2bf(af[i] - hf);
            }
#pragma unroll
            for (int ct = 0; ct < 8; ++ct) {
                short8 bw = *(const short8*)&ws[(ct * 16 + ln) * 40 + lg * 8];
                acc1[ct] = __builtin_amdgcn_mfma_f32_16x16x32_bf16(ah, bw, acc1[ct], 0, 0, 0);
                acc1[ct] = __builtin_amdgcn_mfma_f32_16x16x32_bf16(al, bw, acc1[ct], 0, 0, 0);
            }
        }
        __syncthreads();
#pragma unroll
        for (int ct = 0; ct < 8; ++ct) {
            int c = ct * 16 + ln;
            float bv = b_f1[hh * 128 + c];
#pragma unroll
            for (int rg = 0; rg < 4; ++rg) {
                int r = w * 16 + lg * 4 + rg;
                float hv = fminf(fmaxf(acc1[ct][rg] + bv, 0.f), 6.f);
                hid_s[r * 132 + c] = f2bf(hv);
            }
        }
        __syncthreads();

        for (int kt = 0; kt < 128; kt += 32) {
            __syncthreads();
            *(short8*)&ws[wcol * 40 + wk]     = *(const short8*)&wtf2[(size_t)wcol * 256 + hh * 128 + kt + wk];
            *(short8*)&ws[wcol * 40 + wk + 8] = *(const short8*)&wtf2[(size_t)wcol * 256 + hh * 128 + kt + wk + 8];
            __syncthreads();
            short8 ah = *(const short8*)&hid_s[arow * 132 + kt + lg * 8];
#pragma unroll
            for (int ct = 0; ct < 8; ++ct) {
                short8 bw = *(const short8*)&ws[(ct * 16 + ln) * 40 + lg * 8];
                acc2[ct] = __builtin_amdgcn_mfma_f32_16x16x32_bf16(ah, bw, acc2[ct], 0, 0, 0);
            }
        }
    }

#pragma unroll
    for (int ct = 0; ct < 8; ++ct) {
        int c = ct * 16 + ln;
        float bv = b_f2[c];
#pragma unroll
        for (int rg = 0; rg < 4; ++rg) {
            int r = w * 16 + lg * 4 + rg;
            float v = acc2[ct][rg] + bv + fused_s[r * 132 + c];
            out[(size_t)(r0 + r) * 128 + c] = fminf(fmaxf(v, 0.f), 6.f);
        }
    }
}

// ---------------------------------------------------------------- branchless sorted insert (ascending u32)
__device__ __forceinline__ void ins6(unsigned (&d)[6], unsigned k)
{
#pragma unroll
    for (int t = 0; t < 6; ++t) {
        unsigned lo = d[t] < k ? d[t] : k;
        unsigned hi = d[t] < k ? k : d[t];
        d[t] = lo; k = hi;
    }
}

// ---------------------------------------------------------------- kNN prefilter via MFMA (R11 config, frozen)
__global__ __launch_bounds__(256) void knn_mfma_k(const unsigned short* __restrict__ xh,
                                                  const float* __restrict__ sqn,
                                                  int* __restrict__ cand)
{
    __shared__ char lds[16640];               // 16KB hi tile + 256B biased csq
    char* ldsH = lds;
    float* cs_s = (float*)(lds + 16384);

    int b = blockIdx.x;
    int g = b & 7, r = b >> 3;                // g == XCD id -> per-graph L2 locality
    int chunk = r & 7, qblk = r >> 3;
    int gbase = g * Sg;
    int cbase = chunk * CLEN;
    int qlen = (chunk < 7) ? CLEN : (Sg - 7 * CLEN);  // 520 last
    int ntiles = (qlen + 63) >> 6;                     // 10 or 9
    int nfull = (chunk < 7) ? ntiles : ntiles - 1;
    int tid = threadIdx.x;
    int w = tid >> 6, lane = tid & 63;
    int lg = lane >> 4, ln = lane & 15;
    int q0 = qblk * 128 + w * 32;

    short8 bh[2][4];
#pragma unroll
    for (int s = 0; s < 2; ++s) {
        int q = q0 + s * 16 + ln;
        int qrow = gbase + (q < Sg ? q : Sg - 1);
#pragma unroll
        for (int ks = 0; ks < 4; ++ks)
            bh[s][ks] = *(const short8*)&xh[(size_t)qrow * 128 + ks * 32 + lg * 8];
    }

    int srow = tid >> 4, sslot = tid & 15;
    int sw_st = (srow & 7) << 4;
    int dstoff[4];
    const unsigned short* src[4];
#pragma unroll
    for (int i = 0; i < 4; ++i) {
        int row = i * 16 + srow;
        dstoff[i] = row * 256 + ((sslot * 16) ^ sw_st);
        src[i] = &xh[(size_t)(gbase + cbase + row) * 128 + sslot * 8];
    }
    const float* csrc = &sqn[gbase + cbase];

    unsigned d6a[6], d6b[6];
#pragma unroll
    for (int t = 0; t < 6; ++t) { d6a[t] = 0xFFFFFFFFu; d6b[t] = 0xFFFFFFFFu; }

    for (int t64 = 0; t64 < ntiles; ++t64) {
        __syncthreads();
        if (t64 < nfull) {
#pragma unroll
            for (int i = 0; i < 4; ++i) {
                short8 vh = *(const short8*)src[i];
                src[i] += 64 * 128;
                *(short8*)(ldsH + dstoff[i]) = vh;
            }
            if (tid < 64) cs_s[tid] = csrc[tid] + 1024.0f;
        } else {
            int c0 = cbase + t64 * 64;
#pragma unroll
            for (int i = 0; i < 4; ++i) {
                int cr = c0 + i * 16 + srow;
                if (cr >= Sg) cr = Sg - 1;
                short8 vh = *(const short8*)&xh[(size_t)(gbase + cr) * 128 + sslot * 8];
                *(short8*)(ldsH + dstoff[i]) = vh;
            }
            if (tid < 64) {
                int cl = c0 + tid;
                cs_s[tid] = (cl < cbase + qlen) ? (sqn[gbase + cl] + 1024.0f) : __builtin_inff();
            }
        }
        csrc += 64;
        __syncthreads();

        int c0 = cbase + t64 * 64;
#pragma unroll
        for (int g16 = 0; g16 < 4; ++g16) {
            f32x4 acc0 = {0.f, 0.f, 0.f, 0.f};
            f32x4 acc1 = {0.f, 0.f, 0.f, 0.f};
            int rr = g16 * 16 + ln;
            int rsw = (ln & 7) << 4;
#pragma unroll
            for (int ks = 0; ks < 4; ++ks) {
                short8 ah = *(const short8*)(ldsH + rr * 256 + ((lg * 16 + ks * 64) ^ rsw));
                acc0 = __builtin_amdgcn_mfma_f32_16x16x32_bf16(ah, bh[0][ks], acc0, 0, 0, 0);
                acc1 = __builtin_amdgcn_mfma_f32_16x16x32_bf16(ah, bh[1][ks], acc1, 0, 0, 0);
            }
            f32x4 cv = *(const f32x4*)&cs_s[g16 * 16 + lg * 4];
            int idx0 = (c0 - cbase) + g16 * 16 + lg * 4;
#pragma unroll
            for (int rg = 0; rg < 4; ++rg) {
                unsigned ki = (unsigned)(idx0 + rg);
                unsigned k0 = (__float_as_uint(fmaf(-2.f, acc0[rg], cv[rg])) & 0xFFFFF800u) | ki;
                unsigned k1 = (__float_as_uint(fmaf(-2.f, acc1[rg], cv[rg])) & 0xFFFFF800u) | ki;
                ins6(d6a, k0);
                ins6(d6b, k1);
            }
        }
    }

#pragma unroll
    for (int s = 0; s < 2; ++s) {
        unsigned m6[6];
#pragma unroll
        for (int t = 0; t < 6; ++t) m6[t] = s ? d6b[t] : d6a[t];
#pragma unroll
        for (int sg = 1; sg < 4; ++sg)
#pragma unroll
            for (int t = 0; t < 6; ++t) {
                unsigned v = __shfl(s ? d6b[t] : d6a[t], ln + sg * 16);
#pragma unroll
                for (int u = 0; u < 6; ++u) {
                    unsigned lo = m6[u] < v ? m6[u] : v;
                    unsigned hi = m6[u] < v ? v : m6[u];
                    m6[u] = lo; v = hi;
                }
            }
        int q = q0 + s * 16 + ln;
        if (lg == 0 && q < Sg) {
            int* cp = &cand[(size_t)(gbase + q) * NCAND + chunk * 6];
#pragma unroll
            for (int t = 0; t < 6; ++t) cp[t] = gbase + cbase + (int)(m6[t] & 2047u);
        }
    }
}

// ---------------------------------------------------------------- exact fp32 re-rank, wave per query (linear map)
__global__ __launch_bounds__(256) void knn_rerank_k(const float* __restrict__ x,
                                                    const float* __restrict__ sqn,
                                                    const int* __restrict__ cand,
                                                    int* __restrict__ knn_idx)
{
    int w = threadIdx.x >> 6, lane = threadIdx.x & 63;
    int grp = lane >> 4, gl = lane & 15;
    int q = blockIdx.x * 4 + w;
    float4 qa = *(const float4*)&x[(size_t)q * 128 + gl * 8];
    float4 qb = *(const float4*)&x[(size_t)q * 128 + gl * 8 + 4];
    const int* cp = &cand[(size_t)q * NCAND + grp * 12];

    int ca[12]; unsigned okm = 0;
#pragma unroll
    for (int j = 0; j < 12; ++j) {
        int c = cp[j];
        bool ok = (unsigned)c < (unsigned)N && c != q;
        okm |= (ok ? 1u : 0u) << j;
        ca[j] = ok ? c : 0;
    }

    float d6[6]; int i6[6]; float mx = __builtin_inff(); int sl = 0;
#pragma unroll
    for (int t = 0; t < 6; ++t) { d6[t] = __builtin_inff(); i6[t] = -1; }

    float4 vaA = *(const float4*)&x[(size_t)ca[0] * 128 + gl * 8];
    float4 vbA = *(const float4*)&x[(size_t)ca[0] * 128 + gl * 8 + 4];
#pragma unroll
    for (int j = 0; j < 12; ++j) {
        float4 vaB, vbB;
        if (j < 11) {
            vaB = *(const float4*)&x[(size_t)ca[j + 1] * 128 + gl * 8];
            vbB = *(const float4*)&x[(size_t)ca[j + 1] * 128 + gl * 8 + 4];
        }
        float p = qa.x * vaA.x;
        p = fmaf(qa.y, vaA.y, p); p = fmaf(qa.z, vaA.z, p); p = fmaf(qa.w, vaA.w, p);
        p = fmaf(qb.x, vbA.x, p); p = fmaf(qb.y, vbA.y, p);
        p = fmaf(qb.z, vbA.z, p); p = fmaf(qb.w, vbA.w, p);
#pragma unroll
        for (int off = 1; off < 16; off <<= 1) p += __shfl_xor(p, off);
        float dv = ((okm >> j) & 1u) ? fmaf(-2.f, p, sqn[ca[j]]) : __builtin_inff();
        if (dv < mx) {
#pragma unroll
            for (int t = 0; t < 6; ++t)
                if (t == sl) { d6[t] = dv; i6[t] = ca[j]; }
            float m2 = d6[0]; int s2 = 0;
#pragma unroll
            for (int t = 1; t < 6; ++t)
                if (d6[t] > m2) { m2 = d6[t]; s2 = t; }
            mx = m2; sl = s2;
        }
        vaA = vaB; vbA = vbB;
    }

#pragma unroll
    for (int sg = 1; sg < 4; ++sg) {
#pragma unroll
        for (int t = 0; t < 6; ++t) {
            float dv = __shfl(d6[t], gl + sg * 16);
            int ci = __shfl(i6[t], gl + sg * 16);
            if (grp == 0 && dv < mx) {
#pragma unroll
                for (int u = 0; u < 6; ++u)
                    if (u == sl) { d6[u] = dv; i6[u] = ci; }
                float m2 = d6[0]; int s2 = 0;
#pragma unroll
                for (int u = 1; u < 6; ++u)
                    if (d6[u] > m2) { m2 = d6[u]; s2 = u; }
                mx = m2; sl = s2;
            }
        }
    }
    if (lane < 6) {
        int v;
#pragma unroll
        for (int t = 0; t < 6; ++t) if (t == lane) v = i6[t];
        knn_idx[(size_t)q * 6 + lane] = v;
    }
}

// ---------------------------------------------------------------- CSR build
__global__ __launch_bounds__(256) void hist_k(const int* __restrict__ dstA, int* __restrict__ deg)
{
    int e = blockIdx.x * 256 + threadIdx.x;
    atomicAdd(&deg[dstA[e]], 1);
}

__global__ __launch_bounds__(1024) void scan_k(const int* __restrict__ deg, int* __restrict__ rowptr)
{
    __shared__ int ps[1024];
    int t = threadIdx.x;
    const int chunk = 40;
    int base = t * chunk;
    int s = 0;
    for (int k = 0; k < chunk; ++k) { int i = base + k; if (i < N) s += deg[i]; }
    ps[t] = s;
    __syncthreads();
    for (int off = 1; off < 1024; off <<= 1) {
        int v = (t >= off) ? ps[t - off] : 0;
        __syncthreads();
        ps[t] += v;
        __syncthreads();
    }
    int run = ps[t] - s;
    for (int k = 0; k < chunk; ++k) {
        int i = base + k;
        if (i < N) { rowptr[i] = run; run += deg[i]; }
    }
    if (t == 0) rowptr[N] = E;
}

__global__ __launch_bounds__(256) void scatter_k(const int* __restrict__ srcA, const int* __restrict__ dstA,
                                                 const float* __restrict__ ea,
                                                 const int* __restrict__ rowptr, int* __restrict__ cnt,
                                                 int* __restrict__ csr_src, float* __restrict__ csr_ea)
{
    int e = blockIdx.x * 256 + threadIdx.x;
    int d = dstA[e];
    int pos = rowptr[d] + atomicAdd(&cnt[d], 1);
    csr_src[pos] = srcA[e];
    csr_ea[pos] = ea[e];
}

// ---------------------------------------------------------------- fused GAT (blockIdx.y: 0=spatial, 1=latent; linear map)
__global__ __launch_bounds__(256) void gat_fused_k(
    const float* __restrict__ xl_s, const float* __restrict__ xr_s,
    const int* __restrict__ rowptr, const int* __restrict__ csr_src, const float* __restrict__ csr_ea,
    const float* __restrict__ att_s, const float* __restrict__ wse, const float* __restrict__ bias_s,
    const float* __restrict__ xl_l, const float* __restrict__ xr_l,
    const int* __restrict__ knn, const float* __restrict__ att_l, const float* __restrict__ bias_l,
    float* __restrict__ ch2)
{
    int w = threadIdx.x >> 6, lane = threadIdx.x & 63;
    int dst = blockIdx.x * 4 + w;

    if (blockIdx.y == 0) {
        int base = rowptr[dst];
        int deg = rowptr[dst + 1] - base;
        float xr0 = xr_s[(size_t)dst * 128 + lane], xr1 = xr_s[(size_t)dst * 128 + 64 + lane];
        float at0 = att_s[lane], at1 = att_s[64 + lane];
        float we0 = wse[lane], we1 = wse[64 + lane];

        float eaN = 0.f, v0N = 0.f, v1N = 0.f;
        if (deg > 0) {
            int s0 = csr_src[base];
            eaN = csr_ea[base];
            v0N = xl_s[(size_t)s0 * 128 + lane];
            v1N = xl_s[(size_t)s0 * 128 + 64 + lane];
        }
        float m = -1e30f, ssum = 0.f, o0 = 0.f, o1 = 0.f;
        for (int i = 0; i < deg; ++i) {
            float ea = eaN, v0 = v0N, v1 = v1N;
            if (i + 1 < deg) {
                int sn = csr_src[base + i + 1];
                eaN = csr_ea[base + i + 1];
                v0N = xl_s[(size_t)sn * 128 + lane];
                v1N = xl_s[(size_t)sn * 128 + 64 + lane];
            }
            float h0 = fmaf(ea, we0, v0 + xr0);
            float h1 = fmaf(ea, we1, v1 + xr1);
            h0 = h0 > 0.f ? h0 : 0.2f * h0;
            h1 = h1 > 0.f ? h1 : 0.2f * h1;
            float p = fmaf(h1, at1, h0 * at0);
#pragma unroll
            for (int off = 32; off; off >>= 1) p += __shfl_xor(p, off);
            if (p <= m) {
                float wt = __expf(p - m);
                ssum += wt;
                o0 = fmaf(wt, v0, o0);
                o1 = fmaf(wt, v1, o1);
            } else {
                float sc = __expf(m - p);
                ssum = fmaf(ssum, sc, 1.f);
                o0 = fmaf(o0, sc, v0);
                o1 = fmaf(o1, sc, v1);
                m = p;
            }
        }
        float inv = deg > 0 ? 1.f / ssum : 0.f;
        ch2[(size_t)dst * 256 + lane]      = fmaf(o0, inv, bias_s[lane]);
        ch2[(size_t)dst * 256 + 64 + lane] = fmaf(o1, inv, bias_s[64 + lane]);
    } else {
        float xr0 = xr_l[(size_t)dst * 128 + lane], xr1 = xr_l[(size_t)dst * 128 + 64 + lane];
        float at0 = att_l[lane], at1 = att_l[64 + lane];
        int s[7];
#pragma unroll
        for (int j = 0; j < 6; ++j) s[j] = knn[(size_t)dst * 6 + j];
        s[6] = dst;
        float l[7];
#pragma unroll
        for (int j = 0; j < 7; ++j) {
            float h0 = xl_l[(size_t)s[j] * 128 + lane] + xr0;
            float h1 = xl_l[(size_t)s[j] * 128 + 64 + lane] + xr1;
            h0 = h0 > 0.f ? h0 : 0.2f * h0;
            h1 = h1 > 0.f ? h1 : 0.2f * h1;
            float p = h0 * at0 + h1 * at1;
#pragma unroll
            for (int off = 32; off; off >>= 1) p += __shfl_xor(p, off);
            l[j] = p;
        }
        float m = l[0];
#pragma unroll
        for (int j = 1; j < 7; ++j) m = fmaxf(m, l[j]);
        float sum = 0.f;
#pragma unroll
        for (int j = 0; j < 7; ++j) { l[j] = __expf(l[j] - m); sum += l[j]; }
        float inv = 1.f / sum;
        float o0 = 0.f, o1 = 0.f;
#pragma unroll
        for (int j = 0; j < 7; ++j) {
            float a = l[j] * inv;
            o0 = fmaf(a, xl_l[(size_t)s[j] * 128 + lane], o0);
            o1 = fmaf(a, xl_l[(size_t)s[j] * 128 + 64 + lane], o1);
        }
        ch2[(size_t)dst * 256 + 128 + lane] = o0 + bias_l[lane];
        ch2[(size_t)dst * 256 + 192 + lane] = o1 + bias_l[64 + lane];
    }
}

// ---------------------------------------------------------------- launch
extern "C" void kernel_launch(void* const* d_in, const int* in_sizes, int n_in,
                              void* d_out, int out_size, void* d_ws, size_t ws_size,
                              hipStream_t stream)
{
    const float* x      = (const float*)d_in[0];
    const int*   ei     = (const int*)  d_in[1];
    const float* eattr  = (const float*)d_in[2];
    const float* W_sl   = (const float*)d_in[4];
    const float* b_sl   = (const float*)d_in[5];
    const float* W_sr   = (const float*)d_in[6];
    const float* b_sr   = (const float*)d_in[7];
    const float* att_s  = (const float*)d_in[8];
    const float* W_se   = (const float*)d_in[9];
    const float* bias_s = (const float*)d_in[10];
    const float* W_ll   = (const float*)d_in[11];
    const float* b_ll   = (const float*)d_in[12];
    const float* W_lr   = (const float*)d_in[13];
    const float* b_lr   = (const float*)d_in[14];
    const float* att_l  = (const float*)d_in[15];
    const float* bias_l = (const float*)d_in[16];
    const float* W_c    = (const float*)d_in[17];
    const float* b_c    = (const float*)d_in[18];
    const float* W_f1   = (const float*)d_in[19];
    const float* b_f1   = (const float*)d_in[20];
    const float* W_f2   = (const float*)d_in[21];
    const float* b_f2   = (const float*)d_in[22];
    float* out = (float*)d_out;

    char* wp = (char*)d_ws;
    auto take = [&](size_t bytes) { char* p = wp; wp += (bytes + 255) & ~(size_t)255; return p; };
    float* xl_s    = (float*)take((size_t)N * D * 4);
    float* xr_s    = (float*)take((size_t)N * D * 4);
    float* xl_l    = (float*)take((size_t)N * D * 4);
    float* xr_l    = (float*)take((size_t)N * D * 4);
    float* ch2     = (float*)take((size_t)N * 2 * D * 4);
    float* sqn     = (float*)take((size_t)N * 4);
    int*   knn_idx = (int*)  take((size_t)N * KN * 4);
    int*   deg     = (int*)  take((size_t)N * 4);
    int*   rowptr  = (int*)  take((size_t)(N + 1) * 4);
    int*   csr_src = (int*)  take((size_t)E * 4);
    float* csr_ea  = (float*)take((size_t)E * 4);
    unsigned short* x_hi = (unsigned short*)take((size_t)N * D * 2);
    int*   knn_cand = (int*)take((size_t)N * NCAND * 4);
    unsigned short* wt4  = (unsigned short*)take(65536 * 2);
    unsigned short* wtc  = (unsigned short*)take(32768 * 2);
    unsigned short* wtf1 = (unsigned short*)take(32768 * 2);
    unsigned short* wtf2 = (unsigned short*)take(32768 * 2);
    if ((size_t)(wp - (char*)d_ws) > ws_size) return;

    dim3 blk(256);

    // weight transpose + bf16 cast (one-shot, all matrices)
    w_prep_k<<<dim3(640), blk, 0, stream>>>(W_sl, W_sr, W_ll, W_lr, W_c, W_f1, W_f2,
                                            wt4, wtc, wtf1, wtf2);

    // fused node transforms (4 outputs) + xh/sqn prep folded into y==0 blocks
    gemm4_mfma_k<<<dim3(N / 64, 4), blk, 0, stream>>>(x, wt4,
        b_sl, b_sr, b_ll, b_lr, xl_s, xr_s, xl_l, xr_l, x_hi, sqn);

    // kNN graph: bf16 MFMA prefilter (8 chunks) -> exact fp32 re-rank
    knn_mfma_k<<<dim3(Bg * 40 * 8), blk, 0, stream>>>(x_hi, sqn, knn_cand);
    knn_rerank_k<<<dim3(N / 4), blk, 0, stream>>>(x, sqn, knn_cand, knn_idx);

    // CSR of spatial edges by dst
    hipMemsetAsync(deg, 0, (size_t)N * 4, stream);
    hist_k<<<dim3(E / 256), blk, 0, stream>>>(ei + E, deg);
    scan_k<<<dim3(1), dim3(1024), 0, stream>>>(deg, rowptr);
    hipMemsetAsync(deg, 0, (size_t)N * 4, stream);  // reuse as scatter cursor
    scatter_k<<<dim3(E / 256), blk, 0, stream>>>(ei, ei + E, eattr, rowptr, deg, csr_src, csr_ea);

    // both GAT channels in one launch -> ch2 = [ch_sp | ch_lat]
    gat_fused_k<<<dim3(N / 4, 2), blk, 0, stream>>>(xl_s, xr_s, rowptr, csr_src, csr_ea,
                                                    att_s, W_se, bias_s,
                                                    xl_l, xr_l, knn_idx, att_l, bias_l, ch2);

    // fused tail: fusion + FFN1 + FFN2 in one kernel (no HBM intermediates)
    tail_mfma_k<<<dim3(N / 64), blk, 0, stream>>>(ch2, x, wtc, wtf1, wtf2,
                                                  b_c, b_f1, b_f2, out);
}